// Round 8
// baseline (37.165 us; speedup 1.0000x reference)
//
#include <hip/hip_runtime.h>
#include <math.h>

// u: (B=8, T=64, NY=256, NX=256) f32. Residual: (B, 62, NY, NX), center t+1.
// x/y zero-padded, t not padded. Output: sqrt(sum(res^2)).
#define B_    8
#define T_    64
#define NY_   256
#define NX_   256
#define PS_   (NY_ * NX_)

#define YB_     4                   // residual rows per wave
#define WPB_    4                   // waves per block
#define ROWS_   (WPB_ * YB_)        // 16 residual rows per block
#define HR_     (ROWS_ + 2)         // 18 staged rows per plane (with y-halo)
#define TCHUNKS 8                   // 7 chunks of 8 t-steps + 1 of 6
#define NTHREADS 256
#define YBLOCKS (NY_ / ROWS_)       // 16
#define NBLOCKS (B_ * YBLOCKS * TCHUNKS)   // 1024 blocks = 4/CU, one cohort

__device__ __forceinline__ float4 loadf4(const float* p) { return *(const float4*)p; }

// Async global->LDS stage of one plane's 18 rows, spread over the block's 4 waves.
// LDS dest is wave-uniform base + lane*16 (HW rule); global src is per-lane.
__device__ __forceinline__ void stage_plane(const float* __restrict__ plane,
                                            float* __restrict__ dst /* [HR_][NX_] */,
                                            int Y0, int w, int lane) {
    typedef __attribute__((address_space(1))) const unsigned int gu32;
    typedef __attribute__((address_space(3))) unsigned int lu32;
    #pragma unroll
    for (int j = 0; j < 4; ++j) {
        int r = w + 4 * j;                       // rows 0..15
        int y = Y0 - 1 + r;
        y = y < 0 ? 0 : (y > NY_ - 1 ? NY_ - 1 : y);
        const float* gp = plane + y * NX_ + lane * 4;
        __builtin_amdgcn_global_load_lds((gu32*)gp, (lu32*)(dst + r * NX_), 16, 0, 0);
    }
    if (w < 2) {                                  // rows 16,17 (wave-uniform branch)
        int r = 16 + w;
        int y = Y0 - 1 + r;
        y = y > NY_ - 1 ? NY_ - 1 : y;
        const float* gp = plane + y * NX_ + lane * 4;
        __builtin_amdgcn_global_load_lds((gu32*)gp, (lu32*)(dst + r * NX_), 16, 0, 0);
    }
}

// R6-proven register roll (tm[4] + c[6], masks at halo) + LDS-staged tp plane.
// Do NOT register-pipeline (R4: spills) and do NOT fuse finalize (R5: remat).
template <int LEN>
__global__ __launch_bounds__(NTHREADS, 4)
void pinn_residual_partial(const float* __restrict__ u, float* __restrict__ partial,
                           int tc_base) {
    __shared__ float buf[2][HR_][NX_];            // 2 * 18 * 1 KiB = 36864 B

    const float a   = 0.04f;                      // 1/DH^2
    const float kdt = 250000.0f / 4840000.0f;     // (1/DT^2)/C^2
    const float k2  = 2.0f * kdt - 4.0f * a;

    const int lane = threadIdx.x & 63;
    const int w    = threadIdx.x >> 6;

    // XCD-aware mapping (proven: FETCH 123->82 MB): b = bid&7 pins each batch
    // (16.8 MB) to one XCD's L2. NBLOCKS per launch is 8*YBLOCKS*k, bijective.
    const int b     = blockIdx.x & 7;
    const int inner = blockIdx.x >> 3;
    const int yb    = inner & (YBLOCKS - 1);      // 0..15
    const int tc    = tc_base + (inner >> 4);
    const int t0    = tc * 8;
    const int Y0    = yb * ROWS_;

    const int yfirst = Y0 + 4 * w;                // wave's first residual row
    const float m0 = (yfirst > 0)          ? 1.0f : 0.0f;
    const float m5 = (yfirst + 3 < NY_ - 1)? 1.0f : 0.0f;
    const float xl = (lane > 0)  ? 1.0f : 0.0f;
    const float xr = (lane < 63) ? 1.0f : 0.0f;

    const float* plane0 = u + ((size_t)b * T_ + t0) * PS_;

    // Preload tm (plane t0, center rows) and c (plane t0+1, rows with halo) to regs.
    float4 tm[YB_], c[YB_ + 2];
    #pragma unroll
    for (int i = 0; i < YB_; ++i)
        tm[i] = loadf4(plane0 + (yfirst + i) * NX_ + lane * 4);
    const float* plane1 = plane0 + PS_;
    #pragma unroll
    for (int j = 0; j < YB_ + 2; ++j) {
        int y = yfirst - 1 + j;
        y = y < 0 ? 0 : (y > NY_ - 1 ? NY_ - 1 : y);
        c[j] = loadf4(plane1 + y * NX_ + lane * 4);
    }
    c[0].x *= m0; c[0].y *= m0; c[0].z *= m0; c[0].w *= m0;
    c[5].x *= m5; c[5].y *= m5; c[5].z *= m5; c[5].w *= m5;

    // Prologue: stage plane t0+2 into buf[0].
    stage_plane(plane0 + 2 * PS_, &buf[0][0][0], Y0, w, lane);
    __syncthreads();

    float acc = 0.0f;
    int cur = 0;
    #pragma unroll
    for (int k = 0; k < LEN; ++k) {
        // Issue next plane's stage before touching this iteration's data:
        // it completes under the compute below, drained by the end barrier.
        if (k + 1 < LEN)
            stage_plane(plane0 + (size_t)(3 + k) * PS_, &buf[cur ^ 1][0][0], Y0, w, lane);

        // tp plane rows for this wave from LDS (r = 4w .. 4w+5).
        float4 nn[YB_ + 2];
        #pragma unroll
        for (int j = 0; j < YB_ + 2; ++j)
            nn[j] = *(const float4*)&buf[cur][4 * w + j][lane * 4];
        nn[0].x *= m0; nn[0].y *= m0; nn[0].z *= m0; nn[0].w *= m0;
        nn[5].x *= m5; nn[5].y *= m5; nn[5].z *= m5; nn[5].w *= m5;

        #pragma unroll
        for (int i = 0; i < YB_; ++i) {
            float4 ctr = c[i + 1], up = c[i], dn = c[i + 2];
            float4 t = tm[i], nf = nn[i + 1];
            float cl = __shfl_up(ctr.w, 1, 64) * xl;
            float cr = __shfl_down(ctr.x, 1, 64) * xr;

            {
                float s2 = cl + ctr.y + up.x + dn.x;
                float r = fmaf(s2, a, fmaf(t.x + nf.x, -kdt, ctr.x * k2));
                acc = fmaf(r, r, acc);
            }
            {
                float s2 = ctr.x + ctr.z + up.y + dn.y;
                float r = fmaf(s2, a, fmaf(t.y + nf.y, -kdt, ctr.y * k2));
                acc = fmaf(r, r, acc);
            }
            {
                float s2 = ctr.y + ctr.w + up.z + dn.z;
                float r = fmaf(s2, a, fmaf(t.z + nf.z, -kdt, ctr.z * k2));
                acc = fmaf(r, r, acc);
            }
            {
                float s2 = ctr.z + cr + up.w + dn.w;
                float r = fmaf(s2, a, fmaf(t.w + nf.w, -kdt, ctr.w * k2));
                acc = fmaf(r, r, acc);
            }
        }

        #pragma unroll
        for (int i = 0; i < YB_; ++i) tm[i] = c[i + 1];
        #pragma unroll
        for (int j = 0; j < YB_ + 2; ++j) c[j] = nn[j];

        if (k + 1 < LEN) {
            __syncthreads();       // drains stage (vmcnt) + all buf[cur] readers
            cur ^= 1;
        }
    }

    #pragma unroll
    for (int off = 32; off > 0; off >>= 1)
        acc += __shfl_down(acc, off, 64);

    __shared__ float lds[WPB_];
    if (lane == 0) lds[w] = acc;
    __syncthreads();
    if (threadIdx.x == 0) {
        float bs = lds[0] + lds[1] + lds[2] + lds[3];
        partial[blockIdx.x] = bs;   // every slot written every launch
    }
}

#define NB_MAIN (B_ * YBLOCKS * (TCHUNKS - 1))   // 896 blocks, LEN=8
#define NB_TAIL (B_ * YBLOCKS)                   // 128 blocks, LEN=6
#define NPART   (NB_MAIN + NB_TAIL)              // 1024 partials

__global__ __launch_bounds__(NTHREADS)
void pinn_finalize(const float* __restrict__ partial, float* __restrict__ out) {
    float s = 0.0f;
    for (int i = threadIdx.x; i < NPART; i += NTHREADS)
        s += partial[i];
    #pragma unroll
    for (int off = 32; off > 0; off >>= 1)
        s += __shfl_down(s, off, 64);
    __shared__ float lds[NTHREADS / 64];
    int lane = threadIdx.x & 63;
    int wid  = threadIdx.x >> 6;
    if (lane == 0) lds[wid] = s;
    __syncthreads();
    if (threadIdx.x == 0) {
        float bs = 0.0f;
        #pragma unroll
        for (int q = 0; q < NTHREADS / 64; ++q) bs += lds[q];
        out[0] = sqrtf(bs);
    }
}

extern "C" void kernel_launch(void* const* d_in, const int* in_sizes, int n_in,
                              void* d_out, int out_size, void* d_ws, size_t ws_size,
                              hipStream_t stream) {
    const float* u = (const float*)d_in[0];
    float* partial = (float*)d_ws;              // NPART floats = 4 KiB scratch
    float* out     = (float*)d_out;

    // Chunks 0..6 (LEN=8) and chunk 7 (LEN=6) as two instantiations.
    pinn_residual_partial<8><<<NB_MAIN, NTHREADS, 0, stream>>>(u, partial, 0);
    pinn_residual_partial<6><<<NB_TAIL, NTHREADS, 0, stream>>>(u, partial + NB_MAIN, 7);
    pinn_finalize<<<1, NTHREADS, 0, stream>>>(partial, out);
}

// Round 9
// 31.147 us; speedup vs baseline: 1.1932x; 1.1932x over previous
//
#include <hip/hip_runtime.h>
#include <math.h>

// u: (B=8, T=64, NY=256, NX=256) f32. Residual: (B, 62, NY, NX), center t+1.
// x/y zero-padded, t not padded. Output: sqrt(sum(res^2)).
#define B_    8
#define T_    64
#define NY_   256
#define NX_   256
#define PS_   (NY_ * NX_)

// One wave = YB consecutive y-rows x full x-row (64 lanes x float4 = 256).
#define YB_     4
#define NSTRIP  (NY_ / YB_)                 // 64 strips
#define TCHUNKS 8                           // 7 chunks of 8 t-steps + 1 of 6
#define NWAVES  (B_ * NSTRIP * TCHUNKS)     // 4096 waves = 16/CU
#define NTHREADS 256
#define NBLOCKS  (NWAVES / 4)               // 1024 blocks (8 XCDs x 128)

__device__ __forceinline__ float4 loadf4(const float* p) { return *(const float4*)p; }

// One t-step: residual rows from (tm, c, nf), then roll tm<-c centers, c<-nf.
__device__ __forceinline__ void step_t(float4 (&tm)[YB_], float4 (&c)[YB_ + 2],
                                       const float4 (&nf)[YB_ + 2], float& acc,
                                       float xl, float xr) {
    const float a   = 0.04f;                        // 1/DH^2
    const float kdt = 250000.0f / 4840000.0f;       // (1/DT^2)/C^2
    const float k2  = 2.0f * kdt - 4.0f * a;        // coeff of center

    #pragma unroll
    for (int i = 0; i < YB_; ++i) {
        float4 ctr = c[i + 1], up = c[i], dn = c[i + 2];
        float4 t = tm[i], n = nf[i + 1];
        float cl = __shfl_up(ctr.w, 1, 64) * xl;
        float cr = __shfl_down(ctr.x, 1, 64) * xr;

        {
            float s2 = cl + ctr.y + up.x + dn.x;
            float r = fmaf(s2, a, fmaf(t.x + n.x, -kdt, ctr.x * k2));
            acc = fmaf(r, r, acc);
        }
        {
            float s2 = ctr.x + ctr.z + up.y + dn.y;
            float r = fmaf(s2, a, fmaf(t.y + n.y, -kdt, ctr.y * k2));
            acc = fmaf(r, r, acc);
        }
        {
            float s2 = ctr.y + ctr.w + up.z + dn.z;
            float r = fmaf(s2, a, fmaf(t.z + n.z, -kdt, ctr.z * k2));
            acc = fmaf(r, r, acc);
        }
        {
            float s2 = ctr.z + cr + up.w + dn.w;
            float r = fmaf(s2, a, fmaf(t.w + n.w, -kdt, ctr.w * k2));
            acc = fmaf(r, r, acc);
        }
    }
    #pragma unroll
    for (int i = 0; i < YB_; ++i) tm[i] = c[i + 1];
    #pragma unroll
    for (int j = 0; j < YB_ + 2; ++j) c[j] = nf[j];
}

// R6 structure with the main loop processing TWO planes per iteration: all 12
// row-loads issue back-to-back, so global latency is paid once per 2 t-steps.
// Peak live state 22 float4 (~88 VGPR) — inside the (256,4) 128-VGPR budget.
// Do NOT add a pipeline stage (R4: allocator flip -> spills), do NOT fuse the
// finalize (R5: 52-VGPR remat), do NOT barrier-couple waves (R8).
template <int LEN>   // LEN must be even
__device__ __forceinline__ float strip_accum(const float* __restrict__ u,
                                             int b, int ys, int t0, int lane) {
    static_assert(LEN % 2 == 0, "LEN even");
    const int y0 = ys * YB_;
    const float m0 = (ys > 0)           ? 1.0f : 0.0f;
    const float m5 = (ys < NSTRIP - 1)  ? 1.0f : 0.0f;
    const float xl = (lane > 0)  ? 1.0f : 0.0f;
    const float xr = (lane < 63) ? 1.0f : 0.0f;

    int yoff[YB_ + 2];
    #pragma unroll
    for (int j = 0; j < YB_ + 2; ++j) {
        int y = y0 - 1 + j;
        y = y < 0 ? 0 : (y > NY_ - 1 ? NY_ - 1 : y);
        yoff[j] = y * NX_;
    }

    const float* pl = u + ((size_t)b * T_ + t0) * PS_ + lane * 4;

    float4 tm[YB_], c[YB_ + 2];
    #pragma unroll
    for (int i = 0; i < YB_; ++i) tm[i] = loadf4(pl + yoff[i + 1]);
    const float* p1 = pl + PS_;
    #pragma unroll
    for (int j = 0; j < YB_ + 2; ++j) c[j] = loadf4(p1 + yoff[j]);
    c[0].x *= m0; c[0].y *= m0; c[0].z *= m0; c[0].w *= m0;
    c[YB_+1].x *= m5; c[YB_+1].y *= m5; c[YB_+1].z *= m5; c[YB_+1].w *= m5;

    float acc = 0.0f;
    const float* pn = pl + 2 * PS_;
    #pragma unroll
    for (int k = 0; k < LEN; k += 2) {
        // Batch both planes' loads: 12 independent global_load_dwordx4 in flight.
        float4 nA[YB_ + 2], nB[YB_ + 2];
        #pragma unroll
        for (int j = 0; j < YB_ + 2; ++j) nA[j] = loadf4(pn + yoff[j]);
        #pragma unroll
        for (int j = 0; j < YB_ + 2; ++j) nB[j] = loadf4(pn + PS_ + yoff[j]);
        nA[0].x *= m0; nA[0].y *= m0; nA[0].z *= m0; nA[0].w *= m0;
        nA[YB_+1].x *= m5; nA[YB_+1].y *= m5; nA[YB_+1].z *= m5; nA[YB_+1].w *= m5;
        nB[0].x *= m0; nB[0].y *= m0; nB[0].z *= m0; nB[0].w *= m0;
        nB[YB_+1].x *= m5; nB[YB_+1].y *= m5; nB[YB_+1].z *= m5; nB[YB_+1].w *= m5;

        step_t(tm, c, nA, acc, xl, xr);
        step_t(tm, c, nB, acc, xl, xr);
        pn += 2 * PS_;
    }
    return acc;
}

__global__ __launch_bounds__(NTHREADS, 4)
void pinn_residual_partial(const float* __restrict__ u, float* __restrict__ partial) {
    const int lane = threadIdx.x & 63;
    const int w    = threadIdx.x >> 6;

    // XCD-aware mapping (proven: FETCH 123->82 MB): b = bid&7 pins each batch
    // (16.8 MB) to one XCD's L2. 1024 blocks = 8 x 128, bijective.
    const int b     = blockIdx.x & 7;
    const int inner = blockIdx.x >> 3;             // 0..127
    const int wl    = inner * 4 + w;               // 0..511 within batch
    const int ys = wl & (NSTRIP - 1);              // 4 consecutive strips per block
    const int tc = wl >> 6;                        // 0..7
    const int t0 = tc * 8;

    float s;
    if (tc < TCHUNKS - 1) s = strip_accum<8>(u, b, ys, t0, lane);
    else                  s = strip_accum<6>(u, b, ys, t0, lane);

    #pragma unroll
    for (int off = 32; off > 0; off >>= 1)
        s += __shfl_down(s, off, 64);

    __shared__ float lds[NTHREADS / 64];
    if (lane == 0) lds[w] = s;
    __syncthreads();
    if (threadIdx.x == 0) {
        float bs = lds[0] + lds[1] + lds[2] + lds[3];
        partial[blockIdx.x] = bs;   // every slot written every launch
    }
}

__global__ __launch_bounds__(NTHREADS)
void pinn_finalize(const float* __restrict__ partial, float* __restrict__ out) {
    float s = 0.0f;
    for (int i = threadIdx.x; i < NBLOCKS; i += NTHREADS)
        s += partial[i];
    #pragma unroll
    for (int off = 32; off > 0; off >>= 1)
        s += __shfl_down(s, off, 64);
    __shared__ float lds[NTHREADS / 64];
    int lane = threadIdx.x & 63;
    int wid  = threadIdx.x >> 6;
    if (lane == 0) lds[wid] = s;
    __syncthreads();
    if (threadIdx.x == 0) {
        float bs = 0.0f;
        #pragma unroll
        for (int q = 0; q < NTHREADS / 64; ++q) bs += lds[q];
        out[0] = sqrtf(bs);
    }
}

extern "C" void kernel_launch(void* const* d_in, const int* in_sizes, int n_in,
                              void* d_out, int out_size, void* d_ws, size_t ws_size,
                              hipStream_t stream) {
    const float* u = (const float*)d_in[0];
    float* partial = (float*)d_ws;              // NBLOCKS floats = 4 KiB scratch
    float* out     = (float*)d_out;

    pinn_residual_partial<<<NBLOCKS, NTHREADS, 0, stream>>>(u, partial);
    pinn_finalize<<<1, NTHREADS, 0, stream>>>(partial, out);
}